// Round 1
// baseline (1598.039 us; speedup 1.0000x reference)
//
#include <hip/hip_runtime.h>
#include <math.h>

#define TT 512
#define BB 512
#define CC 32
#define CIN 33
#define HH 128
#define GG 512
#define EPSF 1e-12f

// ---------------------------------------------------------------------------
// Kernel 1: s[t] = mean_c std_b(x[:,t,c], ddof=1)   -> ws[0..511]
// ---------------------------------------------------------------------------
__global__ void std_kernel(const float* __restrict__ x, float* __restrict__ ws) {
    const int t = blockIdx.x;
    const int c = threadIdx.x & 31;
    const int sl = threadIdx.x >> 5;          // 8 slices of 64 batch rows
    float sum = 0.f, sq = 0.f;
    for (int k = 0; k < 64; ++k) {
        const int b = sl * 64 + k;
        float v = x[((size_t)b * TT + t) * CC + c];
        sum += v;
        sq  = fmaf(v, v, sq);
    }
    __shared__ float rs[8][32];
    __shared__ float rq[8][32];
    rs[sl][c] = sum; rq[sl][c] = sq;
    __syncthreads();
    if (threadIdx.x < 32) {
        float S = 0.f, Q = 0.f;
        for (int i = 0; i < 8; ++i) { S += rs[i][threadIdx.x]; Q += rq[i][threadIdx.x]; }
        float mean = S / 512.0f;
        float var  = (Q - 512.0f * mean * mean) / 511.0f;
        rs[0][threadIdx.x] = sqrtf(fmaxf(var, 0.f));
    }
    __syncthreads();
    if (threadIdx.x == 0) {
        float m = 0.f;
        for (int i = 0; i < 32; ++i) m += rs[0][i];
        ws[t] = m / 32.0f;
    }
}

// ---------------------------------------------------------------------------
// Kernel 2: spectral-norm sigmas -> ws[512]=sig_ih, ws[513]=sig_hh, ws[514]=sig_fc
// sigma = ||Wv||^2/(||Wv||+eps), v = (W^T u)/(||W^T u||+eps)
// ---------------------------------------------------------------------------
__global__ void sigma_kernel(const float* __restrict__ w_ih, const float* __restrict__ u_ih,
                             const float* __restrict__ w_hh, const float* __restrict__ u_hh,
                             const float* __restrict__ fc_w, const float* __restrict__ u_fc,
                             float* __restrict__ ws) {
    const int tid = threadIdx.x;
    __shared__ float red[512];
    __shared__ float vv[128];

    // ---- sigma_hh : W [512,128] ----
    {
        const int c = tid & 127, q = tid >> 7;
        float part = 0.f;
        for (int g = q * 128; g < q * 128 + 128; ++g)
            part = fmaf(w_hh[g * HH + c], u_hh[g], part);
        red[tid] = part;
        __syncthreads();
        if (tid < 128) vv[tid] = red[tid] + red[tid + 128] + red[tid + 256] + red[tid + 384];
        __syncthreads();
        red[tid] = (tid < 128) ? vv[tid] * vv[tid] : 0.f;
        __syncthreads();
        for (int s = 64; s >= 1; s >>= 1) { if (tid < s) red[tid] += red[tid + s]; __syncthreads(); }
        const float nv = sqrtf(red[0]);
        __syncthreads();
        if (tid < 128) vv[tid] = vv[tid] / (nv + EPSF);
        __syncthreads();
        float wv = 0.f;
        for (int c2 = 0; c2 < 128; ++c2) wv = fmaf(w_hh[tid * HH + c2], vv[c2], wv);
        red[tid] = wv * wv;
        __syncthreads();
        for (int s = 256; s >= 1; s >>= 1) { if (tid < s) red[tid] += red[tid + s]; __syncthreads(); }
        if (tid == 0) { float ns2 = red[0]; ws[513] = ns2 / (sqrtf(ns2) + EPSF); }
        __syncthreads();
    }
    // ---- sigma_ih : W [512,33] ----
    {
        float part = 0.f;
        if (tid < CIN) {
            for (int g = 0; g < 512; ++g) part = fmaf(w_ih[g * CIN + tid], u_ih[g], part);
            red[tid] = part;
        }
        __syncthreads();
        if (tid == 0) {
            float n2 = 0.f;
            for (int i = 0; i < CIN; ++i) n2 += red[i] * red[i];
            red[400] = sqrtf(n2);
        }
        __syncthreads();
        const float nv = red[400];
        if (tid < CIN) vv[tid] = red[tid] / (nv + EPSF);
        __syncthreads();
        float wv = 0.f;
        for (int c2 = 0; c2 < CIN; ++c2) wv = fmaf(w_ih[tid * CIN + c2], vv[c2], wv);
        red[tid] = wv * wv;
        __syncthreads();
        for (int s = 256; s >= 1; s >>= 1) { if (tid < s) red[tid] += red[tid + s]; __syncthreads(); }
        if (tid == 0) { float ns2 = red[0]; ws[512] = ns2 / (sqrtf(ns2) + EPSF); }
        __syncthreads();
    }
    // ---- sigma_fc : W [1,128] ----
    {
        red[tid] = (tid < 128) ? fc_w[tid] * fc_w[tid] : 0.f;
        __syncthreads();
        for (int s = 64; s >= 1; s >>= 1) { if (tid < s) red[tid] += red[tid + s]; __syncthreads(); }
        if (tid == 0) {
            float nw2 = red[0];
            float u0  = u_fc[0];
            float nv  = fabsf(u0) * sqrtf(nw2);           // ||W^T u||
            float wv  = u0 * nw2 / (nv + EPSF);           // W @ v  (scalar)
            ws[514]   = wv * wv / (fabsf(wv) + EPSF);
        }
    }
}

// ---------------------------------------------------------------------------
// Kernel 3: persistent fused LSTM + attention + FC.
// One block = 2 batch rows, 512 threads. Thread g owns Whh row g (128 fp32 in
// regs) and Wih row g (33 fp32). h broadcast via LDS float4 (conflict-free).
// Online softmax for attention pooling; never materializes h[B,T,H].
// ---------------------------------------------------------------------------
__global__ __launch_bounds__(512, 2) void lstm_kernel(
    const float* __restrict__ x,
    const float* __restrict__ w_ih, const float* __restrict__ w_hh,
    const float* __restrict__ b_ih, const float* __restrict__ b_hh,
    const float* __restrict__ attn_w, const float* __restrict__ attn_b,
    const float* __restrict__ fc_w, const float* __restrict__ fc_b,
    const float* __restrict__ ws,
    float* __restrict__ out)
{
    const int tid = threadIdx.x;
    const int b0  = blockIdx.x * 2;
    const float sig_ih = ws[512], sig_hh = ws[513], sig_fc = ws[514];

    // per-thread weight row (registers)
    float w[HH];
#pragma unroll
    for (int j = 0; j < HH; ++j) w[j] = w_hh[tid * HH + j] / sig_hh;
    float wxr[36];
#pragma unroll
    for (int c = 0; c < CIN; ++c) wxr[c] = w_ih[tid * CIN + c] / sig_ih;
    wxr[33] = wxr[34] = wxr[35] = 0.f;
    const float bias  = b_ih[tid] + b_hh[tid];
    const int   gtype = tid >> 7;            // 0:i 1:f 2:g 3:o

    __shared__ __align__(16) float hs[2][HH];
    __shared__ __align__(16) float xs[2][36];
    __shared__ float gact[2][GG];
    __shared__ float wred[4];
    __shared__ float ab[2][2];
    __shared__ float Sf[2];

    const int ub = tid >> 7;                 // update-phase batch (tid<256)
    const int uj = tid & 127;
    float creg = 0.f, Preg = 0.f, attw = 0.f, fcwj = 0.f;
    if (tid < 256) {
        hs[ub][uj] = 0.f;
        attw = attn_w[uj];
        fcwj = fc_w[uj];
    }
    float mreg = -INFINITY, Sreg = 0.f;      // owned by tid<2
    const float attb = attn_b[0];

    // x prefetch registers (threads 0..15: 2 rows x 8 float4)
    const int lb = (tid >> 3) & 1;
    const int lc = tid & 7;
    float4 xf = make_float4(0.f, 0.f, 0.f, 0.f);
    if (tid < 16)
        xf = reinterpret_cast<const float4*>(x + ((size_t)(b0 + lb) * TT + 0) * CC)[lc];
    float sv = ws[0];

    for (int t = 0; t < TT; ++t) {
        if (tid < 16) reinterpret_cast<float4*>(&xs[lb][0])[lc] = xf;
        if (tid == 16) {
            xs[0][32] = sv; xs[1][32] = sv;
            xs[0][33] = xs[0][34] = xs[0][35] = 0.f;
            xs[1][33] = xs[1][34] = xs[1][35] = 0.f;
        }
        __syncthreads();                                   // A: xs[t], h[t-1] visible
        if (t + 1 < TT) {
            if (tid < 16)
                xf = reinterpret_cast<const float4*>(x + ((size_t)(b0 + lb) * TT + (t + 1)) * CC)[lc];
            if (tid == 16) sv = ws[t + 1];
        }
        // ---- gates: bias + Wih.x + Whh.h (two batch rows) ----
        float a00 = bias, a01 = 0.f, a10 = bias, a11 = 0.f;   // split chains
        const float4* h0 = reinterpret_cast<const float4*>(&hs[0][0]);
        const float4* h1 = reinterpret_cast<const float4*>(&hs[1][0]);
#pragma unroll
        for (int jc = 0; jc < 32; jc += 2) {
            float4 a = h0[jc],     b4 = h1[jc];
            float4 a2 = h0[jc + 1], b42 = h1[jc + 1];
            a00 = fmaf(w[4*jc+0], a.x, a00);  a00 = fmaf(w[4*jc+1], a.y, a00);
            a00 = fmaf(w[4*jc+2], a.z, a00);  a00 = fmaf(w[4*jc+3], a.w, a00);
            a10 = fmaf(w[4*jc+0], b4.x, a10); a10 = fmaf(w[4*jc+1], b4.y, a10);
            a10 = fmaf(w[4*jc+2], b4.z, a10); a10 = fmaf(w[4*jc+3], b4.w, a10);
            a01 = fmaf(w[4*jc+4], a2.x, a01); a01 = fmaf(w[4*jc+5], a2.y, a01);
            a01 = fmaf(w[4*jc+6], a2.z, a01); a01 = fmaf(w[4*jc+7], a2.w, a01);
            a11 = fmaf(w[4*jc+4], b42.x, a11); a11 = fmaf(w[4*jc+5], b42.y, a11);
            a11 = fmaf(w[4*jc+6], b42.z, a11); a11 = fmaf(w[4*jc+7], b42.w, a11);
        }
        const float4* x0 = reinterpret_cast<const float4*>(&xs[0][0]);
        const float4* x1 = reinterpret_cast<const float4*>(&xs[1][0]);
#pragma unroll
        for (int cc = 0; cc < 9; ++cc) {
            float4 a = x0[cc], b4 = x1[cc];
            a01 = fmaf(wxr[4*cc+0], a.x, a01);  a01 = fmaf(wxr[4*cc+1], a.y, a01);
            a01 = fmaf(wxr[4*cc+2], a.z, a01);  a01 = fmaf(wxr[4*cc+3], a.w, a01);
            a11 = fmaf(wxr[4*cc+0], b4.x, a11); a11 = fmaf(wxr[4*cc+1], b4.y, a11);
            a11 = fmaf(wxr[4*cc+2], b4.z, a11); a11 = fmaf(wxr[4*cc+3], b4.w, a11);
        }
        float acc0 = a00 + a01, acc1 = a10 + a11;
        float act0, act1;
        if (gtype == 2) { act0 = tanhf(acc0); act1 = tanhf(acc1); }
        else            { act0 = 1.f / (1.f + __expf(-acc0)); act1 = 1.f / (1.f + __expf(-acc1)); }
        gact[0][tid] = act0; gact[1][tid] = act1;
        __syncthreads();                                   // B: gates visible
        // ---- state update + attention partial ----
        float hn = 0.f;
        if (tid < 256) {
            float ig = gact[ub][uj];
            float fg = gact[ub][128 + uj];
            float gg = gact[ub][256 + uj];
            float og = gact[ub][384 + uj];
            creg = fmaf(fg, creg, ig * gg);
            hn   = og * tanhf(creg);
            hs[ub][uj] = hn;
            float pv = attw * hn;
#pragma unroll
            for (int off = 32; off >= 1; off >>= 1) pv += __shfl_xor(pv, off, 64);
            if ((tid & 63) == 0) wred[tid >> 6] = pv;
        }
        __syncthreads();                                   // C: wred visible
        if (tid < 2) {
            float logit = wred[2 * tid] + wred[2 * tid + 1] + attb;
            float mn    = fmaxf(mreg, logit);
            float alpha = __expf(mreg - mn);
            float beta  = __expf(logit - mn);
            Sreg = Sreg * alpha + beta;
            mreg = mn;
            ab[tid][0] = alpha; ab[tid][1] = beta;
        }
        __syncthreads();                                   // D: alpha/beta visible
        if (tid < 256) Preg = fmaf(Preg, ab[ub][0], ab[ub][1] * hn);
    }

    // ---- epilogue: pooled @ (fc_w/sigma_fc)^T + fc_b ----
    if (tid < 2) Sf[tid] = Sreg;
    __syncthreads();
    if (tid < 256) {
        float val = (Preg / Sf[ub]) * (fcwj / sig_fc);
#pragma unroll
        for (int off = 32; off >= 1; off >>= 1) val += __shfl_xor(val, off, 64);
        if ((tid & 63) == 0) wred[tid >> 6] = val;
    }
    __syncthreads();
    if (tid < 2) out[b0 + tid] = wred[2 * tid] + wred[2 * tid + 1] + fc_b[0];
}

// ---------------------------------------------------------------------------
extern "C" void kernel_launch(void* const* d_in, const int* in_sizes, int n_in,
                              void* d_out, int out_size, void* d_ws, size_t ws_size,
                              hipStream_t stream) {
    const float* x      = (const float*)d_in[0];
    const float* w_ih   = (const float*)d_in[1];
    const float* u_ih   = (const float*)d_in[2];
    const float* w_hh   = (const float*)d_in[3];
    const float* u_hh   = (const float*)d_in[4];
    const float* b_ih   = (const float*)d_in[5];
    const float* b_hh   = (const float*)d_in[6];
    const float* attn_w = (const float*)d_in[7];
    const float* attn_b = (const float*)d_in[8];
    const float* fc_w   = (const float*)d_in[9];
    const float* u_fc   = (const float*)d_in[10];
    const float* fc_b   = (const float*)d_in[11];
    float* ws  = (float*)d_ws;
    float* out = (float*)d_out;

    std_kernel<<<TT, 256, 0, stream>>>(x, ws);
    sigma_kernel<<<1, 512, 0, stream>>>(w_ih, u_ih, w_hh, u_hh, fc_w, u_fc, ws);
    lstm_kernel<<<BB / 2, 512, 0, stream>>>(x, w_ih, w_hh, b_ih, b_hh,
                                            attn_w, attn_b, fc_w, fc_b, ws, out);
}

// Round 2
// 1488.453 us; speedup vs baseline: 1.0736x; 1.0736x over previous
//
#include <hip/hip_runtime.h>
#include <math.h>

#define TT 512
#define BB 512
#define CC 32
#define CIN 33
#define HH 128
#define GG 512
#define EPSF 1e-12f

typedef short short8 __attribute__((ext_vector_type(8)));
typedef short short4v __attribute__((ext_vector_type(4)));
typedef float f32x4 __attribute__((ext_vector_type(4)));

#define MFMA16(a, b, c) __builtin_amdgcn_mfma_f32_16x16x32_bf16(a, b, c, 0, 0, 0)

__device__ __forceinline__ unsigned short f2bf(float f) {
    unsigned u = __float_as_uint(f);
    unsigned r = (u + 0x7fffu + ((u >> 16) & 1u)) >> 16;
    return (unsigned short)r;
}
__device__ __forceinline__ float bf2f(unsigned short s) {
    return __uint_as_float(((unsigned)s) << 16);
}
__device__ __forceinline__ float fsig(float x) { return 1.f / (1.f + __expf(-x)); }
__device__ __forceinline__ float ftanh(float x) { return 1.f - 2.f / (1.f + __expf(2.f * x)); }

// ---------------------------------------------------------------------------
// Kernel 1: s[t] = mean_c std_b(x[:,t,c], ddof=1)   -> ws[0..511]
// ---------------------------------------------------------------------------
__global__ void std_kernel(const float* __restrict__ x, float* __restrict__ ws) {
    const int t = blockIdx.x;
    const int c = threadIdx.x & 31;
    const int sl = threadIdx.x >> 5;
    float sum = 0.f, sq = 0.f;
    for (int k = 0; k < 64; ++k) {
        const int b = sl * 64 + k;
        float v = x[((size_t)b * TT + t) * CC + c];
        sum += v;
        sq  = fmaf(v, v, sq);
    }
    __shared__ float rs[8][32];
    __shared__ float rq[8][32];
    rs[sl][c] = sum; rq[sl][c] = sq;
    __syncthreads();
    if (threadIdx.x < 32) {
        float S = 0.f, Q = 0.f;
        for (int i = 0; i < 8; ++i) { S += rs[i][threadIdx.x]; Q += rq[i][threadIdx.x]; }
        float mean = S / 512.0f;
        float var  = (Q - 512.0f * mean * mean) / 511.0f;
        rs[0][threadIdx.x] = sqrtf(fmaxf(var, 0.f));
    }
    __syncthreads();
    if (threadIdx.x == 0) {
        float m = 0.f;
        for (int i = 0; i < 32; ++i) m += rs[0][i];
        ws[t] = m / 32.0f;
    }
}

// ---------------------------------------------------------------------------
// Kernel 2: sigmas -> ws[512]=sig_ih, ws[513]=sig_hh, ws[514]=sig_fc
// ---------------------------------------------------------------------------
__global__ void sigma_kernel(const float* __restrict__ w_ih, const float* __restrict__ u_ih,
                             const float* __restrict__ w_hh, const float* __restrict__ u_hh,
                             const float* __restrict__ fc_w, const float* __restrict__ u_fc,
                             float* __restrict__ ws) {
    const int tid = threadIdx.x;
    __shared__ float red[512];
    __shared__ float vv[128];

    {   // sigma_hh
        const int c = tid & 127, q = tid >> 7;
        float part = 0.f;
        for (int g = q * 128; g < q * 128 + 128; ++g)
            part = fmaf(w_hh[g * HH + c], u_hh[g], part);
        red[tid] = part;
        __syncthreads();
        if (tid < 128) vv[tid] = red[tid] + red[tid + 128] + red[tid + 256] + red[tid + 384];
        __syncthreads();
        red[tid] = (tid < 128) ? vv[tid] * vv[tid] : 0.f;
        __syncthreads();
        for (int s = 64; s >= 1; s >>= 1) { if (tid < s) red[tid] += red[tid + s]; __syncthreads(); }
        const float nv = sqrtf(red[0]);
        __syncthreads();
        if (tid < 128) vv[tid] = vv[tid] / (nv + EPSF);
        __syncthreads();
        float wv = 0.f;
        for (int c2 = 0; c2 < 128; ++c2) wv = fmaf(w_hh[tid * HH + c2], vv[c2], wv);
        red[tid] = wv * wv;
        __syncthreads();
        for (int s = 256; s >= 1; s >>= 1) { if (tid < s) red[tid] += red[tid + s]; __syncthreads(); }
        if (tid == 0) { float ns2 = red[0]; ws[513] = ns2 / (sqrtf(ns2) + EPSF); }
        __syncthreads();
    }
    {   // sigma_ih
        float part = 0.f;
        if (tid < CIN) {
            for (int g = 0; g < 512; ++g) part = fmaf(w_ih[g * CIN + tid], u_ih[g], part);
            red[tid] = part;
        }
        __syncthreads();
        if (tid == 0) {
            float n2 = 0.f;
            for (int i = 0; i < CIN; ++i) n2 += red[i] * red[i];
            red[400] = sqrtf(n2);
        }
        __syncthreads();
        const float nv = red[400];
        if (tid < CIN) vv[tid] = red[tid] / (nv + EPSF);
        __syncthreads();
        float wv = 0.f;
        for (int c2 = 0; c2 < CIN; ++c2) wv = fmaf(w_ih[tid * CIN + c2], vv[c2], wv);
        red[tid] = wv * wv;
        __syncthreads();
        for (int s = 256; s >= 1; s >>= 1) { if (tid < s) red[tid] += red[tid + s]; __syncthreads(); }
        if (tid == 0) { float ns2 = red[0]; ws[512] = ns2 / (sqrtf(ns2) + EPSF); }
        __syncthreads();
    }
    {   // sigma_fc
        red[tid] = (tid < 128) ? fc_w[tid] * fc_w[tid] : 0.f;
        __syncthreads();
        for (int s = 64; s >= 1; s >>= 1) { if (tid < s) red[tid] += red[tid + s]; __syncthreads(); }
        if (tid == 0) {
            float nw2 = red[0];
            float u0  = u_fc[0];
            float nv  = fabsf(u0) * sqrtf(nw2);
            float wv  = u0 * nw2 / (nv + EPSF);
            ws[514]   = wv * wv / (fabsf(wv) + EPSF);
        }
    }
}

// ---------------------------------------------------------------------------
// Kernel 3: MFMA LSTM. 32 blocks x 16 batch rows, 512 threads (8 waves).
// gates[16,512] = [h|x] @ W^T via split-bf16 3-term mfma_f32_16x16x32_bf16.
// Weights stationary in VGPRs (B-frags). h round-trips LDS as bf16 hi/lo
// planes. Wave w owns N-tiles {w,w+8,w+16,w+24} = {i,f,g,o} of its own 16
// h-columns -> activations fully in-register. Online-softmax attention.
// ---------------------------------------------------------------------------
__global__ __launch_bounds__(512, 2) void lstm_mfma(
    const float* __restrict__ x,
    const float* __restrict__ w_ih, const float* __restrict__ w_hh,
    const float* __restrict__ b_ih, const float* __restrict__ b_hh,
    const float* __restrict__ attn_w, const float* __restrict__ attn_b,
    const float* __restrict__ fc_w, const float* __restrict__ fc_b,
    const float* __restrict__ ws,
    float* __restrict__ out)
{
    const int tid = threadIdx.x;
    const int w   = tid >> 6;          // wave 0..7
    const int l   = tid & 63;          // lane
    const int m   = l & 15;            // A-row / B-col / D-col index
    const int q   = l >> 4;            // quad 0..3
    const int b0  = blockIdx.x * 16;
    const int jcol = 16 * w + m;       // this lane's h column

    const float rih = 1.f / ws[512];
    const float rhh = 1.f / ws[513];
    const float rfc = 1.f / ws[514];
    const float attb = attn_b[0];

    // LDS: double-buffered h planes (bf16 hi/lo), x planes, softmax scratch
    __shared__ __align__(16) short hsH[2][16][136];
    __shared__ __align__(16) short hsL[2][16][136];
    __shared__ __align__(16) short xsH[2][16][40];
    __shared__ __align__(16) short xsL[2][16][40];
    __shared__ float ab[2][16];
    __shared__ float Sf[16];

    // ---- stationary weights: B-frags BH/BL[p][kt], p=gate-type, kt=K-tile ----
    short8 BH[4][5], BL[4][5];
    float biasg[4], w32g[4];
#pragma unroll
    for (int p = 0; p < 4; ++p) {
        const int g = 16 * w + 128 * p + m;
        float tmp[8];
#pragma unroll
        for (int kt = 0; kt < 4; ++kt) {
            const float* src = w_hh + (size_t)g * HH + kt * 32 + q * 8;
#pragma unroll
            for (int i = 0; i < 8; ++i) tmp[i] = src[i] * rhh;
#pragma unroll
            for (int i = 0; i < 8; ++i) {
                unsigned short h = f2bf(tmp[i]);
                BH[p][kt][i] = (short)h;
                BL[p][kt][i] = (short)f2bf(tmp[i] - bf2f(h));
            }
        }
        {
            const float* src = w_ih + (size_t)g * CIN + q * 8;
#pragma unroll
            for (int i = 0; i < 8; ++i) tmp[i] = src[i] * rih;
#pragma unroll
            for (int i = 0; i < 8; ++i) {
                unsigned short h = f2bf(tmp[i]);
                BH[p][4][i] = (short)h;
                BL[p][4][i] = (short)f2bf(tmp[i] - bf2f(h));
            }
        }
        w32g[p]  = w_ih[(size_t)g * CIN + 32] * rih;
        biasg[p] = b_ih[g] + b_hh[g];
    }
    const float fcwj = fc_w[jcol] * rfc;

    // attention-dot constants for logit phase (lane role: row rrow, chunk kc)
    const int rrow = 2 * w + (l >> 5);
    const int kc   = l & 31;
    float aw[4];
#pragma unroll
    for (int i = 0; i < 4; ++i) aw[i] = attn_w[kc * 4 + i];

    // zero h_{-1} (buffer 1)
    for (int i = tid; i < 16 * 136; i += 512) { hsH[1][0][i] = 0; hsL[1][0][i] = 0; }
    // stage x for t=0 into buffer 0
    if (tid < 128) {
        const int r = tid >> 3, c4 = tid & 7;
        float4 xv = *reinterpret_cast<const float4*>(x + ((size_t)(b0 + r) * TT + 0) * CC + c4 * 4);
        short4v hi, lo;
        float v[4] = {xv.x, xv.y, xv.z, xv.w};
#pragma unroll
        for (int i = 0; i < 4; ++i) {
            unsigned short h = f2bf(v[i]);
            hi[i] = (short)h; lo[i] = (short)f2bf(v[i] - bf2f(h));
        }
        *(short4v*)&xsH[0][r][c4 * 4] = hi;
        *(short4v*)&xsL[0][r][c4 * 4] = lo;
    }

    float c_st[4] = {0.f, 0.f, 0.f, 0.f};
    float P[4]    = {0.f, 0.f, 0.f, 0.f};
    float hprev[4] = {0.f, 0.f, 0.f, 0.f};
    float mreg = -INFINITY, Sreg = 0.f;
    __syncthreads();

    for (int t = 0; t < TT; ++t) {
        const int hr = (t + 1) & 1;    // buffer holding h_{t-1}
        const int hw = t & 1;          // buffer to write h_t
        const float s_t = ws[t];

        // prefetch next x (global)
        float4 xv;
        const int xr = tid >> 3, xc4 = tid & 7;
        if (tid < 128 && t + 1 < TT)
            xv = *reinterpret_cast<const float4*>(x + ((size_t)(b0 + xr) * TT + (t + 1)) * CC + xc4 * 4);

        // ---- logits for h_{t-1} (all waves, 2 rows each) ----
        if (t > 0) {
            float acc = 0.f;
            short4v hh = *(const short4v*)&hsH[hr][rrow][kc * 4];
            short4v ll = *(const short4v*)&hsL[hr][rrow][kc * 4];
#pragma unroll
            for (int i = 0; i < 4; ++i) {
                float hv = bf2f((unsigned short)hh[i]) + bf2f((unsigned short)ll[i]);
                acc = fmaf(aw[i], hv, acc);
            }
#pragma unroll
            for (int off = 1; off < 32; off <<= 1) acc += __shfl_xor(acc, off, 64);
            float logit = acc + attb;
            float mn = fmaxf(mreg, logit);
            float alpha = __expf(mreg - mn);
            float beta  = __expf(logit - mn);
            Sreg = Sreg * alpha + beta;
            mreg = mn;
            if (kc == 0) { ab[0][rrow] = alpha; ab[1][rrow] = beta; }
        }

        // ---- C init + MFMA ----
        f32x4 acc0, acc1, acc2, acc3;
        {
            float c0 = fmaf(w32g[0], s_t, biasg[0]);
            float c1 = fmaf(w32g[1], s_t, biasg[1]);
            float c2 = fmaf(w32g[2], s_t, biasg[2]);
            float c3 = fmaf(w32g[3], s_t, biasg[3]);
            acc0 = (f32x4){c0, c0, c0, c0};
            acc1 = (f32x4){c1, c1, c1, c1};
            acc2 = (f32x4){c2, c2, c2, c2};
            acc3 = (f32x4){c3, c3, c3, c3};
        }
#pragma unroll
        for (int kt = 0; kt < 5; ++kt) {
            short8 ah, al;
            if (kt < 4) {
                ah = *(const short8*)&hsH[hr][m][kt * 32 + q * 8];
                al = *(const short8*)&hsL[hr][m][kt * 32 + q * 8];
            } else {
                ah = *(const short8*)&xsH[t & 1][m][q * 8];
                al = *(const short8*)&xsL[t & 1][m][q * 8];
            }
            acc0 = MFMA16(ah, BH[0][kt], acc0);
            acc1 = MFMA16(ah, BH[1][kt], acc1);
            acc2 = MFMA16(ah, BH[2][kt], acc2);
            acc3 = MFMA16(ah, BH[3][kt], acc3);
            acc0 = MFMA16(al, BH[0][kt], acc0);
            acc1 = MFMA16(al, BH[1][kt], acc1);
            acc2 = MFMA16(al, BH[2][kt], acc2);
            acc3 = MFMA16(al, BH[3][kt], acc3);
            acc0 = MFMA16(ah, BL[0][kt], acc0);
            acc1 = MFMA16(ah, BL[1][kt], acc1);
            acc2 = MFMA16(ah, BL[2][kt], acc2);
            acc3 = MFMA16(ah, BL[3][kt], acc3);
        }

        __syncthreads();   // S1: ab visible; all A-reads of hr done last iter's rules

        // stage x_{t+1} into buffer (t+1)&1
        if (tid < 128 && t + 1 < TT) {
            short4v hi, lo;
            float v[4] = {xv.x, xv.y, xv.z, xv.w};
#pragma unroll
            for (int i = 0; i < 4; ++i) {
                unsigned short h = f2bf(v[i]);
                hi[i] = (short)h; lo[i] = (short)f2bf(v[i] - bf2f(h));
            }
            *(short4v*)&xsH[(t + 1) & 1][xr][xc4 * 4] = hi;
            *(short4v*)&xsL[(t + 1) & 1][xr][xc4 * 4] = lo;
        }

        // ---- P update with alpha/beta of step t-1 ----
        if (t > 0) {
#pragma unroll
            for (int i = 0; i < 4; ++i) {
                const int r_i = q * 4 + i;
                P[i] = fmaf(P[i], ab[0][r_i], ab[1][r_i] * hprev[i]);
            }
        }

        // ---- activations + state update (rows q*4+i, column jcol) ----
#pragma unroll
        for (int i = 0; i < 4; ++i) {
            float ig = fsig(acc0[i]);
            float fg = fsig(acc1[i]);
            float gg = ftanh(acc2[i]);
            float og = fsig(acc3[i]);
            c_st[i] = fmaf(fg, c_st[i], ig * gg);
            float hv = og * ftanh(c_st[i]);
            hprev[i] = hv;
            unsigned short hh = f2bf(hv);
            const int r_i = q * 4 + i;
            hsH[hw][r_i][jcol] = (short)hh;
            hsL[hw][r_i][jcol] = (short)f2bf(hv - bf2f(hh));
        }

        __syncthreads();   // S3: h_t + x_{t+1} visible
    }

    // ---- epilogue: logit for h_511, final P update, FC projection ----
    {
        float acc = 0.f;
        short4v hh = *(const short4v*)&hsH[1][rrow][kc * 4];
        short4v ll = *(const short4v*)&hsL[1][rrow][kc * 4];
#pragma unroll
        for (int i = 0; i < 4; ++i) {
            float hv = bf2f((unsigned short)hh[i]) + bf2f((unsigned short)ll[i]);
            acc = fmaf(aw[i], hv, acc);
        }
#pragma unroll
        for (int off = 1; off < 32; off <<= 1) acc += __shfl_xor(acc, off, 64);
        float logit = acc + attb;
        float mn = fmaxf(mreg, logit);
        float alpha = __expf(mreg - mn);
        float beta  = __expf(logit - mn);
        Sreg = Sreg * alpha + beta;
        if (kc == 0) { ab[0][rrow] = alpha; ab[1][rrow] = beta; Sf[rrow] = Sreg; }
    }
    __syncthreads();
    float* sc = (float*)&hsH[0][0][0];   // reuse as [16][132] fp32 scratch
#pragma unroll
    for (int i = 0; i < 4; ++i) {
        const int r_i = q * 4 + i;
        float Pv = fmaf(P[i], ab[0][r_i], ab[1][r_i] * hprev[i]);
        sc[r_i * 132 + jcol] = (Pv / Sf[r_i]) * fcwj;
    }
    __syncthreads();
    {
        float acc2 = 0.f;
#pragma unroll
        for (int i = 0; i < 4; ++i) acc2 += sc[rrow * 132 + kc * 4 + i];
#pragma unroll
        for (int off = 1; off < 32; off <<= 1) acc2 += __shfl_xor(acc2, off, 64);
        if (kc == 0) out[b0 + rrow] = acc2 + fc_b[0];
    }
}

// ---------------------------------------------------------------------------
extern "C" void kernel_launch(void* const* d_in, const int* in_sizes, int n_in,
                              void* d_out, int out_size, void* d_ws, size_t ws_size,
                              hipStream_t stream) {
    const float* x      = (const float*)d_in[0];
    const float* w_ih   = (const float*)d_in[1];
    const float* u_ih   = (const float*)d_in[2];
    const float* w_hh   = (const float*)d_in[3];
    const float* u_hh   = (const float*)d_in[4];
    const float* b_ih   = (const float*)d_in[5];
    const float* b_hh   = (const float*)d_in[6];
    const float* attn_w = (const float*)d_in[7];
    const float* attn_b = (const float*)d_in[8];
    const float* fc_w   = (const float*)d_in[9];
    const float* u_fc   = (const float*)d_in[10];
    const float* fc_b   = (const float*)d_in[11];
    float* ws  = (float*)d_ws;
    float* out = (float*)d_out;

    std_kernel<<<TT, 256, 0, stream>>>(x, ws);
    sigma_kernel<<<1, 512, 0, stream>>>(w_ih, u_ih, w_hh, u_hh, fc_w, u_fc, ws);
    lstm_mfma<<<BB / 16, 512, 0, stream>>>(x, w_ih, w_hh, b_ih, b_hh,
                                           attn_w, attn_b, fc_w, fc_b, ws, out);
}